// Round 9
// baseline (42.837 us; speedup 1.0000x reference)
//
#include <hip/hip_runtime.h>
#include <math.h>

#define BSZ 32
#define NPT 8192
#define XB   8         // x-blocks per b1-pair
#define PPT  4         // points per thread (256 thr * 8 blk * 4 = 8192)
#define G    8         // b2-groups
#define B2P (BSZ / G)  // b2 per group = 4
#define NP  (BSZ / 2)  // b1 pairs = 16
#define BPP (XB * G)   // blocks per pair = 64

// ws float layout:
// [0    .. 2047]  part_sq  [pair*128 + half*64 + xb*8 + g]
// [2048 .. 4095]  part_rsq (same indexing)
// [4096 .. 4351]  inlier   [pair*16 + half*8 + xb]       (g==0 blocks)
// [4352 .. 4863]  staged per-b1: [b1*16 + {0:sq,1:rs,2:inl,3:re,4:te}]
// [4864 .. 5119]  pair counters (int), one per 16 floats (64B lines)
// [5120]          global counter (int)
// Counters zeroed each call by hipMemsetAsync; partials/staged written
// unconditionally before their consumers (fence+atomic ordering).
#define CNT_BASE 4864
#define GCNT     5120

template<int CTRL>
__device__ __forceinline__ float dpp_shift_add(float x) {
    union { float f; int i; } u, r;
    u.f = x;
    r.i = __builtin_amdgcn_update_dpp(0, u.i, CTRL, 0xF, 0xF, true);
    return x + r.f;
}
__device__ __forceinline__ float wave64_sum(float x) {
    x = dpp_shift_add<0x111>(x);   // row_shr:1
    x = dpp_shift_add<0x112>(x);   // row_shr:2
    x = dpp_shift_add<0x114>(x);   // row_shr:4
    x = dpp_shift_add<0x118>(x);   // row_shr:8
    x = dpp_shift_add<0x142>(x);   // row_bcast:15
    x = dpp_shift_add<0x143>(x);   // row_bcast:31
    return x;                      // valid in lane 63
}

__device__ __forceinline__ void re_te(const float* __restrict__ T,
                                      const float* __restrict__ Gt,
                                      float& re, float& te) {
    float tr = 0.0f;
    #pragma unroll
    for (int i = 0; i < 3; ++i)
        #pragma unroll
        for (int j = 0; j < 3; ++j)
            tr += T[i * 4 + j] * Gt[i * 4 + j];
    float c = (tr - 1.0f) * 0.5f;
    c = fminf(1.0f, fmaxf(-1.0f, c));
    re = acosf(c) * 57.29577951308232f;
    const float dx = T[3] - Gt[3];
    const float dy = T[7] - Gt[7];
    const float dz = T[11] - Gt[11];
    te = sqrtf(dx * dx + dy * dy + dz * dz) * 100.0f;
}

__global__ __launch_bounds__(256) void fused_kernel(
    const float* __restrict__ trans,
    const float* __restrict__ gt_trans,
    const float* __restrict__ src,
    const float* __restrict__ tgt,
    const float* __restrict__ probs,
    float* __restrict__ ws,
    float* __restrict__ out)
{
    const int xb  = blockIdx.x;
    const int p   = blockIdx.y;       // b1 pair index 0..15
    const int g   = blockIdx.z;
    const int tid = threadIdx.x;
    const int b1a = 2 * p;
    const int b1b = 2 * p + 1;
    const int n0  = (xb * 256 + tid) * PPT;

    const float* Ta = trans + b1a * 16;
    const float a00 = Ta[0], a01 = Ta[1], a02 = Ta[2],  at0 = Ta[3];
    const float a10 = Ta[4], a11 = Ta[5], a12 = Ta[6],  at1 = Ta[7];
    const float a20 = Ta[8], a21 = Ta[9], a22 = Ta[10], at2 = Ta[11];
    const float* Tb = trans + b1b * 16;
    const float b00 = Tb[0], b01 = Tb[1], b02 = Tb[2],  bt0 = Tb[3];
    const float b10 = Tb[4], b11 = Tb[5], b12 = Tb[6],  bt1 = Tb[7];
    const float b20 = Tb[8], b21 = Tb[9], b22 = Tb[10], bt2 = Tb[11];

    float wxA[4], wyA[4], wzA[4], wxB[4], wyB[4], wzB[4];
    {
        const float4* sp = (const float4*)(src + ((size_t)b1a * NPT + n0) * 3);
        const float4 sA = sp[0], sB = sp[1], sC = sp[2];
        const float px[4] = {sA.x, sA.w, sB.z, sC.y};
        const float py[4] = {sA.y, sB.x, sB.w, sC.z};
        const float pz[4] = {sA.z, sB.y, sC.x, sC.w};
        #pragma unroll
        for (int i = 0; i < 4; ++i) {
            wxA[i] = a00 * px[i] + a01 * py[i] + a02 * pz[i] + at0;
            wyA[i] = a10 * px[i] + a11 * py[i] + a12 * pz[i] + at1;
            wzA[i] = a20 * px[i] + a21 * py[i] + a22 * pz[i] + at2;
        }
    }
    {
        const float4* sp = (const float4*)(src + ((size_t)b1b * NPT + n0) * 3);
        const float4 sA = sp[0], sB = sp[1], sC = sp[2];
        const float px[4] = {sA.x, sA.w, sB.z, sC.y};
        const float py[4] = {sA.y, sB.x, sB.w, sC.z};
        const float pz[4] = {sA.z, sB.y, sC.x, sC.w};
        #pragma unroll
        for (int i = 0; i < 4; ++i) {
            wxB[i] = b00 * px[i] + b01 * py[i] + b02 * pz[i] + bt0;
            wyB[i] = b10 * px[i] + b11 * py[i] + b12 * pz[i] + bt1;
            wzB[i] = b20 * px[i] + b21 * py[i] + b22 * pz[i] + bt2;
        }
    }

    float asqA = 0.0f, arsA = 0.0f, asqB = 0.0f, arsB = 0.0f;
    #pragma unroll
    for (int k = 0; k < B2P; ++k) {
        const int b2 = g * B2P + k;
        const float4* gp = (const float4*)(tgt + ((size_t)b2 * NPT + n0) * 3);
        const float4 gA = gp[0], gB = gp[1], gC = gp[2];
        const float gx[4] = {gA.x, gA.w, gB.z, gC.y};
        const float gy[4] = {gA.y, gB.x, gB.w, gC.z};
        const float gz[4] = {gA.z, gB.y, gC.x, gC.w};
        #pragma unroll
        for (int i = 0; i < 4; ++i) {
            {
                const float dx = wxA[i] - gx[i];
                const float dy = wyA[i] - gy[i];
                const float dz = wzA[i] - gz[i];
                const float sq = dx * dx + dy * dy + dz * dz;
                asqA += sq;
                arsA += __builtin_amdgcn_sqrtf(sq);
            }
            {
                const float dx = wxB[i] - gx[i];
                const float dy = wyB[i] - gy[i];
                const float dz = wzB[i] - gz[i];
                const float sq = dx * dx + dy * dy + dz * dz;
                asqB += sq;
                arsB += __builtin_amdgcn_sqrtf(sq);
            }
        }
    }

    asqA = wave64_sum(asqA);
    arsA = wave64_sum(arsA);
    asqB = wave64_sum(asqB);
    arsB = wave64_sum(arsB);

    __shared__ float s_sqA[4], s_rsA[4], s_sqB[4], s_rsB[4];
    __shared__ int   s_fA[4], s_fB[4];
    __shared__ int   s_last, s_fin;
    const int wv = tid >> 6;

    int anyfA = 0, anyfB = 0;
    if (g == 0) {
        const int off = xb * 1024 + tid * 4;
        const float4 pa = *(const float4*)(probs + (size_t)b1a * NPT + off);
        const float4 pb = *(const float4*)(probs + (size_t)b1b * NPT + off);
        const int fa = (pa.x > 0.0f) | (pa.y > 0.0f) | (pa.z > 0.0f) | (pa.w > 0.0f);
        const int fb = (pb.x > 0.0f) | (pb.y > 0.0f) | (pb.z > 0.0f) | (pb.w > 0.0f);
        anyfA = (__ballot(fa) != 0ull);
        anyfB = (__ballot(fb) != 0ull);
    }

    if ((tid & 63) == 63) {
        s_sqA[wv] = asqA; s_rsA[wv] = arsA;
        s_sqB[wv] = asqB; s_rsB[wv] = arsB;
        s_fA[wv] = anyfA; s_fB[wv] = anyfB;
    }
    __syncthreads();

    if (tid == 0) {
        const int sub = xb * 8 + g;
        ws[p * 128 + sub]             = s_sqA[0] + s_sqA[1] + s_sqA[2] + s_sqA[3];
        ws[2048 + p * 128 + sub]      = s_rsA[0] + s_rsA[1] + s_rsA[2] + s_rsA[3];
        ws[p * 128 + 64 + sub]        = s_sqB[0] + s_sqB[1] + s_sqB[2] + s_sqB[3];
        ws[2048 + p * 128 + 64 + sub] = s_rsB[0] + s_rsB[1] + s_rsB[2] + s_rsB[3];
        if (g == 0) {
            ws[4096 + p * 16 + xb]     = (s_fA[0] | s_fA[1] | s_fA[2] | s_fA[3]) ? 1.0f : 0.0f;
            ws[4096 + p * 16 + 8 + xb] = (s_fB[0] | s_fB[1] | s_fB[2] | s_fB[3]) ? 1.0f : 0.0f;
        }
        __threadfence();
        int* cnt = (int*)(ws + CNT_BASE) + p * 16;
        s_last = (atomicAdd(cnt, 1) == BPP - 1);
    }
    __syncthreads();
    if (!s_last) return;

    // ---- pair finalize: reduce this pair's 128+128 partials (4 waves) ----
    __threadfence();  // acquire: see all pairs' partial writes
    __shared__ float s_red[4];   // [0]=sq_a [1]=sq_b [2]=rs_a [3]=rs_b
    {
        const int half = wv & 1;
        const int isRs = wv >> 1;
        const int l = tid & 63;
        float v = ws[isRs * 2048 + p * 128 + half * 64 + l];
        v = wave64_sum(v);
        if (l == 63) s_red[wv] = v;
    }
    __syncthreads();
    if (tid < 2) {
        const int b1 = 2 * p + tid;
        float inl = 0.0f;
        #pragma unroll
        for (int k = 0; k < 8; ++k) inl += ws[4096 + p * 16 + tid * 8 + k];
        float re, te;
        re_te(trans + b1 * 16, gt_trans + b1 * 16, re, te);
        float* st = ws + 4352 + b1 * 16;
        st[0] = (tid == 0) ? s_red[0] : s_red[1];
        st[1] = (tid == 0) ? s_red[2] : s_red[3];
        st[2] = inl;
        st[3] = re;
        st[4] = te;
    }
    __threadfence();
    if (tid == 0) {
        int* gcnt = (int*)(ws + GCNT);
        s_fin = (atomicAdd(gcnt, 1) == NP - 1);
    }
    __syncthreads();
    if (!s_fin) return;

    // ---- global finalize: one wave reduces 32 staged 5-tuples ----
    __threadfence();
    if (tid < 64) {
        float loss_c = 0.0f, recall_c = 0.0f, re_c = 0.0f, te_c = 0.0f, rmse_c = 0.0f;
        if (tid < BSZ) {
            const float* st = ws + 4352 + tid * 16;
            const float bsq = st[0], brs = st[1], inl = st[2], re = st[3], te = st[4];
            const float inv = 1.0f / ((float)BSZ * (float)NPT);
            loss_c   = (inl > 0.5f) ? bsq * inv : 0.0f;
            rmse_c   = brs * inv;
            recall_c = ((te < 30.0f) && (re < 15.0f)) ? 1.0f : 0.0f;
            re_c = re;
            te_c = te;
        }
        loss_c   = wave64_sum(loss_c);
        recall_c = wave64_sum(recall_c);
        re_c     = wave64_sum(re_c);
        te_c     = wave64_sum(te_c);
        rmse_c   = wave64_sum(rmse_c);
        if (tid == 63) {
            out[0] = loss_c / (float)BSZ;
            out[1] = recall_c * 100.0f / (float)BSZ;
            out[2] = re_c / (float)BSZ;
            out[3] = te_c / (float)BSZ;
            out[4] = rmse_c / (float)BSZ;
        }
    }
}

extern "C" void kernel_launch(void* const* d_in, const int* in_sizes, int n_in,
                              void* d_out, int out_size, void* d_ws, size_t ws_size,
                              hipStream_t stream) {
    const float* trans    = (const float*)d_in[0];
    const float* gt_trans = (const float*)d_in[1];
    const float* src      = (const float*)d_in[2];
    const float* tgt      = (const float*)d_in[3];
    const float* probs    = (const float*)d_in[4];
    float* ws  = (float*)d_ws;
    float* out = (float*)d_out;

    // zero the 16 pair counters + global counter (64B-padded int slots)
    hipMemsetAsync((char*)d_ws + CNT_BASE * sizeof(float), 0,
                   (GCNT - CNT_BASE + 16) * sizeof(float), stream);

    dim3 grid(XB, NP, G);
    fused_kernel<<<grid, 256, 0, stream>>>(trans, gt_trans, src, tgt, probs, ws, out);
}

// Round 10
// 12.022 us; speedup vs baseline: 3.5632x; 3.5632x over previous
//
#include <hip/hip_runtime.h>
#include <math.h>

#define BSZ 32
#define NPT 8192
#define XB   8         // x-blocks per b1-pair
#define PPT  4         // points per thread (256 thr * 8 blk * 4 = 8192)
#define G    8         // b2-groups
#define B2P (BSZ / G)  // b2 per group = 4
#define NP  (BSZ / 2)  // b1 pairs = 16

// ws layout (floats):
// [0    .. 2047]  sq  partials  [b1*64 + xb*8 + g]
// [2048 .. 4095]  rsq partials  (same indexing)
// [4096 .. 4351]  inlier partials [b1*8 + xb]  (written by g==0 blocks)
// All slots written unconditionally every call -> no zeroing needed.
// NOTE (platform lesson R4/R8): do NOT attempt in-kernel cross-block
// finalize on MI355X — per-block device fences / same-line atomic bursts
// cost ~30us. Two dispatches is the fast structure.

template<int CTRL>
__device__ __forceinline__ float dpp_shift_add(float x) {
    union { float f; int i; } u, r;
    u.f = x;
    r.i = __builtin_amdgcn_update_dpp(0, u.i, CTRL, 0xF, 0xF, true);
    return x + r.f;
}
__device__ __forceinline__ float wave64_sum(float x) {
    x = dpp_shift_add<0x111>(x);   // row_shr:1
    x = dpp_shift_add<0x112>(x);   // row_shr:2
    x = dpp_shift_add<0x114>(x);   // row_shr:4
    x = dpp_shift_add<0x118>(x);   // row_shr:8
    x = dpp_shift_add<0x142>(x);   // row_bcast:15
    x = dpp_shift_add<0x143>(x);   // row_bcast:31
    return x;                      // valid in lane 63
}
// sum of each aligned 8-lane segment -> valid in lanes 7 mod 8
__device__ __forceinline__ float seg8_sum(float x) {
    x = dpp_shift_add<0x111>(x);
    x = dpp_shift_add<0x112>(x);
    x = dpp_shift_add<0x114>(x);
    return x;
}

__global__ __launch_bounds__(256) void fused_kernel(
    const float* __restrict__ trans,
    const float* __restrict__ src,
    const float* __restrict__ tgt,
    const float* __restrict__ probs,
    float* __restrict__ ws)
{
    const int xb  = blockIdx.x;
    const int p   = blockIdx.y;       // b1 pair index 0..15
    const int g   = blockIdx.z;
    const int tid = threadIdx.x;
    const int b1a = 2 * p;
    const int b1b = 2 * p + 1;
    const int n0  = (xb * 256 + tid) * PPT;

    const float* Ta = trans + b1a * 16;
    const float a00 = Ta[0], a01 = Ta[1], a02 = Ta[2],  at0 = Ta[3];
    const float a10 = Ta[4], a11 = Ta[5], a12 = Ta[6],  at1 = Ta[7];
    const float a20 = Ta[8], a21 = Ta[9], a22 = Ta[10], at2 = Ta[11];
    const float* Tb = trans + b1b * 16;
    const float b00 = Tb[0], b01 = Tb[1], b02 = Tb[2],  bt0 = Tb[3];
    const float b10 = Tb[4], b11 = Tb[5], b12 = Tb[6],  bt1 = Tb[7];
    const float b20 = Tb[8], b21 = Tb[9], b22 = Tb[10], bt2 = Tb[11];

    float wxA[4], wyA[4], wzA[4], wxB[4], wyB[4], wzB[4];
    {
        const float4* sp = (const float4*)(src + ((size_t)b1a * NPT + n0) * 3);
        const float4 sA = sp[0], sB = sp[1], sC = sp[2];
        const float px[4] = {sA.x, sA.w, sB.z, sC.y};
        const float py[4] = {sA.y, sB.x, sB.w, sC.z};
        const float pz[4] = {sA.z, sB.y, sC.x, sC.w};
        #pragma unroll
        for (int i = 0; i < 4; ++i) {
            wxA[i] = a00 * px[i] + a01 * py[i] + a02 * pz[i] + at0;
            wyA[i] = a10 * px[i] + a11 * py[i] + a12 * pz[i] + at1;
            wzA[i] = a20 * px[i] + a21 * py[i] + a22 * pz[i] + at2;
        }
    }
    {
        const float4* sp = (const float4*)(src + ((size_t)b1b * NPT + n0) * 3);
        const float4 sA = sp[0], sB = sp[1], sC = sp[2];
        const float px[4] = {sA.x, sA.w, sB.z, sC.y};
        const float py[4] = {sA.y, sB.x, sB.w, sC.z};
        const float pz[4] = {sA.z, sB.y, sC.x, sC.w};
        #pragma unroll
        for (int i = 0; i < 4; ++i) {
            wxB[i] = b00 * px[i] + b01 * py[i] + b02 * pz[i] + bt0;
            wyB[i] = b10 * px[i] + b11 * py[i] + b12 * pz[i] + bt1;
            wzB[i] = b20 * px[i] + b21 * py[i] + b22 * pz[i] + bt2;
        }
    }

    float asqA = 0.0f, arsA = 0.0f, asqB = 0.0f, arsB = 0.0f;
    #pragma unroll
    for (int k = 0; k < B2P; ++k) {
        const int b2 = g * B2P + k;
        const float4* gp = (const float4*)(tgt + ((size_t)b2 * NPT + n0) * 3);
        const float4 gA = gp[0], gB = gp[1], gC = gp[2];
        const float gx[4] = {gA.x, gA.w, gB.z, gC.y};
        const float gy[4] = {gA.y, gB.x, gB.w, gC.z};
        const float gz[4] = {gA.z, gB.y, gC.x, gC.w};
        #pragma unroll
        for (int i = 0; i < 4; ++i) {
            {
                const float dx = wxA[i] - gx[i];
                const float dy = wyA[i] - gy[i];
                const float dz = wzA[i] - gz[i];
                const float sq = dx * dx + dy * dy + dz * dz;
                asqA += sq;
                arsA += __builtin_amdgcn_sqrtf(sq);
            }
            {
                const float dx = wxB[i] - gx[i];
                const float dy = wyB[i] - gy[i];
                const float dz = wzB[i] - gz[i];
                const float sq = dx * dx + dy * dy + dz * dz;
                asqB += sq;
                arsB += __builtin_amdgcn_sqrtf(sq);
            }
        }
    }

    asqA = wave64_sum(asqA);
    arsA = wave64_sum(arsA);
    asqB = wave64_sum(asqB);
    arsB = wave64_sum(arsB);

    __shared__ float s_sqA[4], s_rsA[4], s_sqB[4], s_rsB[4];
    __shared__ int   s_fA[4], s_fB[4];
    const int wv = tid >> 6;

    int anyfA = 0, anyfB = 0;
    if (g == 0) {
        const int off = xb * 1024 + tid * 4;
        const float4 pa = *(const float4*)(probs + (size_t)b1a * NPT + off);
        const float4 pb = *(const float4*)(probs + (size_t)b1b * NPT + off);
        const int fa = (pa.x > 0.0f) | (pa.y > 0.0f) | (pa.z > 0.0f) | (pa.w > 0.0f);
        const int fb = (pb.x > 0.0f) | (pb.y > 0.0f) | (pb.z > 0.0f) | (pb.w > 0.0f);
        anyfA = (__ballot(fa) != 0ull);
        anyfB = (__ballot(fb) != 0ull);
    }

    if ((tid & 63) == 63) {
        s_sqA[wv] = asqA; s_rsA[wv] = arsA;
        s_sqB[wv] = asqB; s_rsB[wv] = arsB;
        s_fA[wv] = anyfA; s_fB[wv] = anyfB;
    }
    __syncthreads();
    if (tid == 0) {
        const int sub = xb * 8 + g;
        ws[b1a * 64 + sub]        = s_sqA[0] + s_sqA[1] + s_sqA[2] + s_sqA[3];
        ws[2048 + b1a * 64 + sub] = s_rsA[0] + s_rsA[1] + s_rsA[2] + s_rsA[3];
        ws[b1b * 64 + sub]        = s_sqB[0] + s_sqB[1] + s_sqB[2] + s_sqB[3];
        ws[2048 + b1b * 64 + sub] = s_rsB[0] + s_rsB[1] + s_rsB[2] + s_rsB[3];
        if (g == 0) {
            ws[4096 + b1a * 8 + xb] = (s_fA[0] | s_fA[1] | s_fA[2] | s_fA[3]) ? 1.0f : 0.0f;
            ws[4096 + b1b * 8 + xb] = (s_fB[0] | s_fB[1] | s_fB[2] | s_fB[3]) ? 1.0f : 0.0f;
        }
    }
}

__global__ __launch_bounds__(256) void final_kernel(
    const float* __restrict__ ws,
    const float* __restrict__ trans,
    const float* __restrict__ gt_trans,
    float* __restrict__ out)
{
    const int tid = threadIdx.x;   // 256 threads = 4 waves
    // thread t handles b1 = t>>3, slots (t&7)*8 .. +7 (two float4 each array)
    const int b1  = tid >> 3;
    const int seg = tid & 7;

    const float4* aq = (const float4*)(ws + b1 * 64 + seg * 8);
    const float4* rq = (const float4*)(ws + 2048 + b1 * 64 + seg * 8);
    const float4 a0 = aq[0], a1 = aq[1];
    const float4 r0 = rq[0], r1 = rq[1];
    float asum = (a0.x + a0.y) + (a0.z + a0.w) + (a1.x + a1.y) + (a1.z + a1.w);
    float rsum = (r0.x + r0.y) + (r0.z + r0.w) + (r1.x + r1.y) + (r1.z + r1.w);
    float inl  = ws[4096 + tid];   // tid = b1*8 + seg : same mapping

    asum = seg8_sum(asum);
    rsum = seg8_sum(rsum);
    inl  = seg8_sum(inl);

    __shared__ float s_sq[BSZ], s_rs[BSZ], s_in[BSZ];
    if (seg == 7) { s_sq[b1] = asum; s_rs[b1] = rsum; s_in[b1] = inl; }
    __syncthreads();

    if (tid < 64) {
        float loss_c = 0.0f, recall_c = 0.0f, re_c = 0.0f, te_c = 0.0f, rmse_c = 0.0f;
        if (tid < BSZ) {
            const float* T  = trans + tid * 16;
            const float* Gt = gt_trans + tid * 16;
            float tr = 0.0f;
            #pragma unroll
            for (int i = 0; i < 3; ++i)
                #pragma unroll
                for (int j = 0; j < 3; ++j)
                    tr += T[i * 4 + j] * Gt[i * 4 + j];
            float c = (tr - 1.0f) * 0.5f;
            c = fminf(1.0f, fmaxf(-1.0f, c));
            const float re = acosf(c) * 57.29577951308232f;

            const float dx = T[3] - Gt[3];
            const float dy = T[7] - Gt[7];
            const float dz = T[11] - Gt[11];
            const float te = sqrtf(dx * dx + dy * dy + dz * dz) * 100.0f;

            const float inv = 1.0f / ((float)BSZ * (float)NPT);
            loss_c   = (s_in[tid] > 0.5f) ? s_sq[tid] * inv : 0.0f;
            recall_c = ((te < 30.0f) && (re < 15.0f)) ? 1.0f : 0.0f;
            re_c   = re;
            te_c   = te;
            rmse_c = s_rs[tid] * inv;
        }
        loss_c   = wave64_sum(loss_c);
        recall_c = wave64_sum(recall_c);
        re_c     = wave64_sum(re_c);
        te_c     = wave64_sum(te_c);
        rmse_c   = wave64_sum(rmse_c);
        if (tid == 63) {
            out[0] = loss_c / (float)BSZ;
            out[1] = recall_c * 100.0f / (float)BSZ;
            out[2] = re_c / (float)BSZ;
            out[3] = te_c / (float)BSZ;
            out[4] = rmse_c / (float)BSZ;
        }
    }
}

extern "C" void kernel_launch(void* const* d_in, const int* in_sizes, int n_in,
                              void* d_out, int out_size, void* d_ws, size_t ws_size,
                              hipStream_t stream) {
    const float* trans    = (const float*)d_in[0];
    const float* gt_trans = (const float*)d_in[1];
    const float* src      = (const float*)d_in[2];
    const float* tgt      = (const float*)d_in[3];
    const float* probs    = (const float*)d_in[4];
    float* ws  = (float*)d_ws;
    float* out = (float*)d_out;

    dim3 grid(XB, NP, G);
    fused_kernel<<<grid, 256, 0, stream>>>(trans, src, tgt, probs, ws);
    final_kernel<<<1, 256, 0, stream>>>(ws, trans, gt_trans, out);
}